// Round 9
// baseline (116.599 us; speedup 1.0000x reference)
//
#include <hip/hip_runtime.h>
#include <stdint.h>

#define T_TOKENS 8192
#define K_DIM    4096
#define NEXP     64
#define TB       128            // tokens per gemm block (8 waves x 16)
#define KC       64             // k per chunk = 2 MFMA k-steps
#define NREP     2              // K-loop repeats (timing probe; epilogue scales 1/NREP)

typedef short bf16x8 __attribute__((ext_vector_type(8)));
typedef float f32x4  __attribute__((ext_vector_type(4)));

// float -> bf16 (RNE) bit tricks; residual v - bf2f(f2bf(v)) is exact in fp32
__device__ __forceinline__ uint32_t f2bf(float v) {
    uint32_t u = __builtin_bit_cast(uint32_t, v);
    return (u + 0x7fffu + ((u >> 16) & 1u)) >> 16;
}
__device__ __forceinline__ float bf2f(uint32_t b) {
    return __builtin_bit_cast(float, b << 16);
}
struct S3 { short h, l, q; };
__device__ __forceinline__ S3 cvt1(float v) {
    uint32_t hb = f2bf(v); float r  = v - bf2f(hb);
    uint32_t lb = f2bf(r); float r2 = r - bf2f(lb);
    uint32_t qb = f2bf(r2);
    S3 o; o.h = (short)hb; o.l = (short)lb; o.q = (short)qb; return o;
}
__device__ __forceinline__ void cvt8(const float4 a0, const float4 a1,
                                     bf16x8& xh, bf16x8& xl, bf16x8& xq) {
    const float av[8] = {a0.x, a0.y, a0.z, a0.w, a1.x, a1.y, a1.z, a1.w};
#pragma unroll
    for (int j = 0; j < 8; ++j) {
        S3 o = cvt1(av[j]);
        xh[j] = o.h; xl[j] = o.l; xq[j] = o.q;
    }
}

// ---------- kernel 0: W [64][4096] fp32 -> fragment-ordered bf16 terms -------
__global__ void wpack(const float* __restrict__ W, float4* __restrict__ Wf,
                      float* __restrict__ out_counts) {
    const int l     = threadIdx.x;       // 0..63
    const int kstep = blockIdx.x;        // 0..127
    const int etile = blockIdx.y;        // 0..3
    if (kstep == 0 && etile == 0)
        out_counts[l] = 0.f;             // stream-ordered before router_finish
    const int e = etile * 16 + (l & 15);
    const int k = kstep * 32 + (l >> 4) * 8;
    const float* src = W + (size_t)e * K_DIM + k;
    bf16x8 h, l1, l2;
#pragma unroll
    for (int j = 0; j < 8; ++j) {
        S3 o = cvt1(src[j]);
        h[j] = o.h; l1[j] = o.l; l2[j] = o.q;
    }
    const size_t base = ((size_t)(kstep * 4 + etile) * 3) * 64 + l;
    Wf[base]       = __builtin_bit_cast(float4, h);
    Wf[base + 64]  = __builtin_bit_cast(float4, l1);
    Wf[base + 128] = __builtin_bit_cast(float4, l2);
}

// ---------- kernel 1: split-K GEMM (R8 structure), K-loop run NREP times ----
// TIMING PROBE: the whole chunk loop executes NREP times, acc accumulates all
// passes (pass-1 acc is C-in to pass-2 MFMAs -> no DCE), epilogue x 1/NREP.
// T_gemm = (dur_R9 - dur_R8) / (NREP - 1); doubled kernel surfaces in top-5.
__global__ __launch_bounds__(512, 4) void gemm_mfma(
    const float*  __restrict__ x,
    const float4* __restrict__ Wf,
    float* __restrict__ P,          // [S][8192][64]
    int KS)                         // k per slice
{
    __shared__ float4 bbuf[2][1536];     // 48 KB

    const int tid  = threadIdx.x;
    const int l    = tid & 63;
    const int wv   = __builtin_amdgcn_readfirstlane(tid >> 6);
    const int t0   = blockIdx.x * TB;
    const int slice = blockIdx.y;
    const int k0   = slice * KS;
    const int nchunk = KS / KC;

    const float4* x4 = (const float4*)x;
    const int arow = wv * 16 + (l & 15);
    const size_t xg = (size_t)(t0 + arow) * (K_DIM / 4) + (size_t)(k0 >> 2) + ((l >> 4) * 2);
    const size_t bg0 = ((size_t)(k0 >> 5)) * 768;

    f32x4 acc[4];
#pragma unroll
    for (int et = 0; et < 4; ++et) acc[et] = (f32x4){0.f, 0.f, 0.f, 0.f};

    for (int rep = 0; rep < NREP; ++rep) {
        // prologue: B chunk 0 via glds; x chunk 0 to regs
#pragma unroll
        for (int q = 0; q < 3; ++q)
            __builtin_amdgcn_global_load_lds(
                (const __attribute__((address_space(1))) void*)(Wf + bg0 + (wv * 3 + q) * 64 + l),
                (__attribute__((address_space(3))) void*)&bbuf[0][(wv * 3 + q) * 64],
                16, 0, 0);
        float4 xa0 = x4[xg + 0], xa1 = x4[xg + 1];
        float4 xa2 = x4[xg + 8], xa3 = x4[xg + 9];
        asm volatile("s_waitcnt vmcnt(0)" ::: "memory");
        __syncthreads();

        for (int c = 0; c < nchunk; ++c) {
            const int b  = c & 1;
            const int nb = b ^ 1;

            float4 xn0 = xa0, xn1 = xa1, xn2 = xa2, xn3 = xa3;
            if (c + 1 < nchunk) {
                const size_t bo = bg0 + (size_t)(c + 1) * 1536;
#pragma unroll
                for (int q = 0; q < 3; ++q)
                    __builtin_amdgcn_global_load_lds(
                        (const __attribute__((address_space(1))) void*)(Wf + bo + (wv * 3 + q) * 64 + l),
                        (__attribute__((address_space(3))) void*)&bbuf[nb][(wv * 3 + q) * 64],
                        16, 0, 0);
                const size_t xo = xg + (size_t)(c + 1) * 16;
                xn0 = x4[xo + 0]; xn1 = x4[xo + 1];
                xn2 = x4[xo + 8]; xn3 = x4[xo + 9];
            }

            bf16x8 xh0, xl0, xq0, xh1, xl1, xq1;
            cvt8(xa0, xa1, xh0, xl0, xq0);
            cvt8(xa2, xa3, xh1, xl1, xq1);

#pragma unroll
            for (int et = 0; et < 4; ++et) {
                {   // kstep 0
                    const float4* bp = &bbuf[b][et * 192 + l];
                    bf16x8 wh = __builtin_bit_cast(bf16x8, bp[0]);
                    bf16x8 wl = __builtin_bit_cast(bf16x8, bp[64]);
                    bf16x8 wq = __builtin_bit_cast(bf16x8, bp[128]);
                    acc[et] = __builtin_amdgcn_mfma_f32_16x16x32_bf16(xh0, wh, acc[et], 0, 0, 0);
                    acc[et] = __builtin_amdgcn_mfma_f32_16x16x32_bf16(xh0, wl, acc[et], 0, 0, 0);
                    acc[et] = __builtin_amdgcn_mfma_f32_16x16x32_bf16(xh0, wq, acc[et], 0, 0, 0);
                    acc[et] = __builtin_amdgcn_mfma_f32_16x16x32_bf16(xl0, wh, acc[et], 0, 0, 0);
                    acc[et] = __builtin_amdgcn_mfma_f32_16x16x32_bf16(xl0, wl, acc[et], 0, 0, 0);
                    acc[et] = __builtin_amdgcn_mfma_f32_16x16x32_bf16(xq0, wh, acc[et], 0, 0, 0);
                }
                {   // kstep 1
                    const float4* bp = &bbuf[b][768 + et * 192 + l];
                    bf16x8 wh = __builtin_bit_cast(bf16x8, bp[0]);
                    bf16x8 wl = __builtin_bit_cast(bf16x8, bp[64]);
                    bf16x8 wq = __builtin_bit_cast(bf16x8, bp[128]);
                    acc[et] = __builtin_amdgcn_mfma_f32_16x16x32_bf16(xh1, wh, acc[et], 0, 0, 0);
                    acc[et] = __builtin_amdgcn_mfma_f32_16x16x32_bf16(xh1, wl, acc[et], 0, 0, 0);
                    acc[et] = __builtin_amdgcn_mfma_f32_16x16x32_bf16(xh1, wq, acc[et], 0, 0, 0);
                    acc[et] = __builtin_amdgcn_mfma_f32_16x16x32_bf16(xl1, wh, acc[et], 0, 0, 0);
                    acc[et] = __builtin_amdgcn_mfma_f32_16x16x32_bf16(xl1, wl, acc[et], 0, 0, 0);
                    acc[et] = __builtin_amdgcn_mfma_f32_16x16x32_bf16(xq1, wh, acc[et], 0, 0, 0);
                }
            }

            asm volatile("s_waitcnt vmcnt(0)" ::: "memory");
            __syncthreads();
            xa0 = xn0; xa1 = xn1; xa2 = xn2; xa3 = xn3;
        }
        __syncthreads();   // rep boundary: bbuf[0] rewrite next pass
    }

    const float inv = 1.0f / (float)NREP;
    float* Pp = P + (size_t)slice * T_TOKENS * NEXP;
#pragma unroll
    for (int et = 0; et < 4; ++et) {
#pragma unroll
        for (int i = 0; i < 4; ++i) {
            int t = t0 + wv * 16 + (l >> 4) * 4 + i;
            Pp[(size_t)t * NEXP + et * 16 + (l & 15)] = acc[et][i] * inv;
        }
    }
}

// ---------- kernel 2: reduce slices + softmax + argmax + bincount ------------
template <int S>
__global__ __launch_bounds__(256) void router_finish_t(
    const float* __restrict__ P, float* __restrict__ out)
{
    const int lane = threadIdx.x & 63;   // expert
    const int wv   = threadIdx.x >> 6;
    const int t    = blockIdx.x * 4 + wv;

    float lg = 0.f;
#pragma unroll
    for (int s = 0; s < S; ++s)
        lg += P[((size_t)s * T_TOKENS + t) * NEXP + lane];

    float* out_w = out;
    float* out_i = out + T_TOKENS;
    float* out_s = out + 2 * T_TOKENS;
    float* out_c = out + 2 * T_TOKENS + (size_t)T_TOKENS * NEXP;

    float m = lg;
#pragma unroll
    for (int off = 32; off > 0; off >>= 1)
        m = fmaxf(m, __shfl_xor(m, off));
    float p = expf(lg - m);
    float s = p;
#pragma unroll
    for (int off = 32; off > 0; off >>= 1)
        s += __shfl_xor(s, off);
    float sc = p / s;

    float bv = sc; int bi = lane;
#pragma unroll
    for (int off = 32; off > 0; off >>= 1) {
        float ov = __shfl_xor(bv, off);
        int   oi = __shfl_xor(bi, off);
        if (ov > bv || (ov == bv && oi < bi)) { bv = ov; bi = oi; }
    }
    out_s[(size_t)t * NEXP + lane] = sc;
    if (lane == 0) {
        out_w[t] = bv;
        out_i[t] = (float)bi;
        atomicAdd(&out_c[bi], 1.0f);   // counts zeroed by wpack this call
    }
}

extern "C" void kernel_launch(void* const* d_in, const int* in_sizes, int n_in,
                              void* d_out, int out_size, void* d_ws, size_t ws_size,
                              hipStream_t stream)
{
    const float* x = (const float*)d_in[0];
    const float* W = (const float*)d_in[1];
    float* out = (float*)d_out;
    float* out_s = out + 2 * T_TOKENS;
    float* out_c = out + 2 * T_TOKENS + (size_t)T_TOKENS * NEXP;

    const size_t wf_bytes  = (size_t)128 * 4 * 3 * 64 * 16;           // 1.5 MiB
    const size_t per_slice = (size_t)T_TOKENS * NEXP * sizeof(float); // 2 MiB

    int S = 8;
    while (S > 1 && wf_bytes + (size_t)S * per_slice > ws_size) S >>= 1;
    float4* Wf = (float4*)d_ws;
    float* Pbuf;
    if (wf_bytes + per_slice <= ws_size) {
        Pbuf = (float*)((char*)d_ws + wf_bytes);
    } else {
        S = 1;
        Pbuf = out_s;
    }

    wpack<<<dim3(128, 4), 64, 0, stream>>>(W, Wf, out_c);
    gemm_mfma<<<dim3(T_TOKENS / TB, S), 512, 0, stream>>>(x, Wf, Pbuf, K_DIM / S);
    switch (S) {
        case 8: router_finish_t<8><<<T_TOKENS / 4, 256, 0, stream>>>(Pbuf, out); break;
        case 4: router_finish_t<4><<<T_TOKENS / 4, 256, 0, stream>>>(Pbuf, out); break;
        case 2: router_finish_t<2><<<T_TOKENS / 4, 256, 0, stream>>>(Pbuf, out); break;
        default: router_finish_t<1><<<T_TOKENS / 4, 256, 0, stream>>>(Pbuf, out); break;
    }
}

// Round 10
// 95.514 us; speedup vs baseline: 1.2207x; 1.2207x over previous
//
#include <hip/hip_runtime.h>
#include <stdint.h>

#define T_TOKENS 8192
#define K_DIM    4096
#define NEXP     64
#define TB       128            // tokens per gemm block (8 waves x 16)
#define KC       64             // k per chunk = 2 MFMA k-steps

typedef short bf16x8 __attribute__((ext_vector_type(8)));
typedef float f32x4  __attribute__((ext_vector_type(4)));

// float -> bf16 (RNE) bit tricks; residual v - bf2f(f2bf(v)) is exact in fp32
__device__ __forceinline__ uint32_t f2bf(float v) {
    uint32_t u = __builtin_bit_cast(uint32_t, v);
    return (u + 0x7fffu + ((u >> 16) & 1u)) >> 16;
}
__device__ __forceinline__ float bf2f(uint32_t b) {
    return __builtin_bit_cast(float, b << 16);
}
struct S3 { short h, l, q; };
__device__ __forceinline__ S3 cvt1(float v) {
    uint32_t hb = f2bf(v); float r  = v - bf2f(hb);
    uint32_t lb = f2bf(r); float r2 = r - bf2f(lb);
    uint32_t qb = f2bf(r2);
    S3 o; o.h = (short)hb; o.l = (short)lb; o.q = (short)qb; return o;
}
__device__ __forceinline__ void cvt8(const float4 a0, const float4 a1,
                                     bf16x8& xh, bf16x8& xl, bf16x8& xq) {
    const float av[8] = {a0.x, a0.y, a0.z, a0.w, a1.x, a1.y, a1.z, a1.w};
#pragma unroll
    for (int j = 0; j < 8; ++j) {
        S3 o = cvt1(av[j]);
        xh[j] = o.h; xl[j] = o.l; xq[j] = o.q;
    }
}

// ---------- kernel 0: W [64][4096] fp32 -> fragment-ordered bf16 terms -------
__global__ void wpack(const float* __restrict__ W, float4* __restrict__ Wf,
                      float* __restrict__ out_counts) {
    const int l     = threadIdx.x;       // 0..63
    const int kstep = blockIdx.x;        // 0..127
    const int etile = blockIdx.y;        // 0..3
    if (kstep == 0 && etile == 0)
        out_counts[l] = 0.f;             // stream-ordered before router_finish
    const int e = etile * 16 + (l & 15);
    const int k = kstep * 32 + (l >> 4) * 8;
    const float* src = W + (size_t)e * K_DIM + k;
    bf16x8 h, l1, l2;
#pragma unroll
    for (int j = 0; j < 8; ++j) {
        S3 o = cvt1(src[j]);
        h[j] = o.h; l1[j] = o.l; l2[j] = o.q;
    }
    const size_t base = ((size_t)(kstep * 4 + etile) * 3) * 64 + l;
    Wf[base]       = __builtin_bit_cast(float4, h);
    Wf[base + 64]  = __builtin_bit_cast(float4, l1);
    Wf[base + 128] = __builtin_bit_cast(float4, l2);
}

// ---------- kernel 1: split-K GEMM with 2-deep x prefetch + counted vmcnt ----
// T4 pattern: never drain vmcnt to 0 in the main loop. Chunk-end waits
// vmcnt(4): B(c+1) glds + x(c+1) complete (issued a full chunk earlier),
// x(c+2) stays in flight across the barrier -> continuous HBM streaming.
// sched_barrier(0) pins glds-before-x issue order (vmcnt is FIFO-counted).
template <int NCH>
__global__ __launch_bounds__(512, 4) void gemm_mfma(
    const float*  __restrict__ x,
    const float4* __restrict__ Wf,
    float* __restrict__ P)          // [S][8192][64]
{
    static_assert(NCH >= 4, "pipeline needs >=4 chunks");
    __shared__ float4 bbuf[2][1536];     // 48 KB

    const int tid  = threadIdx.x;
    const int l    = tid & 63;
    const int wv   = __builtin_amdgcn_readfirstlane(tid >> 6);
    const int t0   = blockIdx.x * TB;
    const int slice = blockIdx.y;
    const int k0   = slice * (NCH * KC);

    const float4* x4 = (const float4*)x;
    const int arow = wv * 16 + (l & 15);
    const size_t xg = (size_t)(t0 + arow) * (K_DIM / 4) + (size_t)(k0 >> 2) + ((l >> 4) * 2);
    const size_t bg0 = ((size_t)(k0 >> 5)) * 768;

    f32x4 acc[4];
#pragma unroll
    for (int et = 0; et < 4; ++et) acc[et] = (f32x4){0.f, 0.f, 0.f, 0.f};

    // prologue: B(0) glds, then x(0), x(1) (issue order pinned for vmcnt FIFO)
#pragma unroll
    for (int q = 0; q < 3; ++q)
        __builtin_amdgcn_global_load_lds(
            (const __attribute__((address_space(1))) void*)(Wf + bg0 + (wv * 3 + q) * 64 + l),
            (__attribute__((address_space(3))) void*)&bbuf[0][(wv * 3 + q) * 64],
            16, 0, 0);
    __builtin_amdgcn_sched_barrier(0);
    float4 xa0 = x4[xg + 0], xa1 = x4[xg + 1];
    float4 xa2 = x4[xg + 8], xa3 = x4[xg + 9];
    __builtin_amdgcn_sched_barrier(0);
    float4 xn0 = x4[xg + 16], xn1 = x4[xg + 17];
    float4 xn2 = x4[xg + 24], xn3 = x4[xg + 25];
    __builtin_amdgcn_sched_barrier(0);
    asm volatile("s_waitcnt vmcnt(4)" ::: "memory");   // B(0)+x(0) done, x(1) in flight
    __syncthreads();

#pragma unroll
    for (int c = 0; c < NCH; ++c) {
        const int b  = c & 1;
        const int nb = b ^ 1;

        // issue B(c+1) glds FIRST (older in vmcnt FIFO than x(c+2))
        if (c + 1 < NCH) {
            const size_t bo = bg0 + (size_t)(c + 1) * 1536;
#pragma unroll
            for (int q = 0; q < 3; ++q)
                __builtin_amdgcn_global_load_lds(
                    (const __attribute__((address_space(1))) void*)(Wf + bo + (wv * 3 + q) * 64 + l),
                    (__attribute__((address_space(3))) void*)&bbuf[nb][(wv * 3 + q) * 64],
                    16, 0, 0);
        }
        __builtin_amdgcn_sched_barrier(0);
        // issue x(c+2) (newest 4 in FIFO -> excluded by vmcnt(4))
        float4 xm0 = xn0, xm1 = xn1, xm2 = xn2, xm3 = xn3;
        if (c + 2 < NCH) {
            const size_t xo = xg + (size_t)(c + 2) * 16;
            xm0 = x4[xo + 0]; xm1 = x4[xo + 1];
            xm2 = x4[xo + 8]; xm3 = x4[xo + 9];
        }
        __builtin_amdgcn_sched_barrier(0);

        // compute chunk c: convert + 48 MFMA (hides in-flight load latency)
        bf16x8 xh0, xl0, xq0, xh1, xl1, xq1;
        cvt8(xa0, xa1, xh0, xl0, xq0);
        cvt8(xa2, xa3, xh1, xl1, xq1);

#pragma unroll
        for (int et = 0; et < 4; ++et) {
            {   // kstep 0
                const float4* bp = &bbuf[b][et * 192 + l];
                bf16x8 wh = __builtin_bit_cast(bf16x8, bp[0]);
                bf16x8 wl = __builtin_bit_cast(bf16x8, bp[64]);
                bf16x8 wq = __builtin_bit_cast(bf16x8, bp[128]);
                acc[et] = __builtin_amdgcn_mfma_f32_16x16x32_bf16(xh0, wh, acc[et], 0, 0, 0);
                acc[et] = __builtin_amdgcn_mfma_f32_16x16x32_bf16(xh0, wl, acc[et], 0, 0, 0);
                acc[et] = __builtin_amdgcn_mfma_f32_16x16x32_bf16(xh0, wq, acc[et], 0, 0, 0);
                acc[et] = __builtin_amdgcn_mfma_f32_16x16x32_bf16(xl0, wh, acc[et], 0, 0, 0);
                acc[et] = __builtin_amdgcn_mfma_f32_16x16x32_bf16(xl0, wl, acc[et], 0, 0, 0);
                acc[et] = __builtin_amdgcn_mfma_f32_16x16x32_bf16(xq0, wh, acc[et], 0, 0, 0);
            }
            {   // kstep 1
                const float4* bp = &bbuf[b][768 + et * 192 + l];
                bf16x8 wh = __builtin_bit_cast(bf16x8, bp[0]);
                bf16x8 wl = __builtin_bit_cast(bf16x8, bp[64]);
                bf16x8 wq = __builtin_bit_cast(bf16x8, bp[128]);
                acc[et] = __builtin_amdgcn_mfma_f32_16x16x32_bf16(xh1, wh, acc[et], 0, 0, 0);
                acc[et] = __builtin_amdgcn_mfma_f32_16x16x32_bf16(xh1, wl, acc[et], 0, 0, 0);
                acc[et] = __builtin_amdgcn_mfma_f32_16x16x32_bf16(xh1, wq, acc[et], 0, 0, 0);
                acc[et] = __builtin_amdgcn_mfma_f32_16x16x32_bf16(xl1, wh, acc[et], 0, 0, 0);
                acc[et] = __builtin_amdgcn_mfma_f32_16x16x32_bf16(xl1, wl, acc[et], 0, 0, 0);
                acc[et] = __builtin_amdgcn_mfma_f32_16x16x32_bf16(xq1, wh, acc[et], 0, 0, 0);
            }
        }

        // counted wait: B(c+1) + x(c+1) landed; x(c+2) (newest 4) stays in flight
        if (c + 2 < NCH) {
            asm volatile("s_waitcnt vmcnt(4)" ::: "memory");
        } else {
            asm volatile("s_waitcnt vmcnt(0)" ::: "memory");
        }
        __syncthreads();

        // rotate register pipeline
        xa0 = xn0; xa1 = xn1; xa2 = xn2; xa3 = xn3;
        xn0 = xm0; xn1 = xm1; xn2 = xm2; xn3 = xm3;
    }

    // epilogue: C/D map col=lane&15 (expert), row=(lane>>4)*4+i (token)
    float* Pp = P + (size_t)slice * T_TOKENS * NEXP;
#pragma unroll
    for (int et = 0; et < 4; ++et) {
#pragma unroll
        for (int i = 0; i < 4; ++i) {
            int t = t0 + wv * 16 + (l >> 4) * 4 + i;
            Pp[(size_t)t * NEXP + et * 16 + (l & 15)] = acc[et][i];
        }
    }
}

// ---------- kernel 2: reduce slices + softmax + argmax + bincount ------------
template <int S>
__global__ __launch_bounds__(256) void router_finish_t(
    const float* __restrict__ P, float* __restrict__ out)
{
    const int lane = threadIdx.x & 63;   // expert
    const int wv   = threadIdx.x >> 6;
    const int t    = blockIdx.x * 4 + wv;

    float lg = 0.f;
#pragma unroll
    for (int s = 0; s < S; ++s)
        lg += P[((size_t)s * T_TOKENS + t) * NEXP + lane];

    float* out_w = out;
    float* out_i = out + T_TOKENS;
    float* out_s = out + 2 * T_TOKENS;
    float* out_c = out + 2 * T_TOKENS + (size_t)T_TOKENS * NEXP;

    float m = lg;
#pragma unroll
    for (int off = 32; off > 0; off >>= 1)
        m = fmaxf(m, __shfl_xor(m, off));
    float p = expf(lg - m);
    float s = p;
#pragma unroll
    for (int off = 32; off > 0; off >>= 1)
        s += __shfl_xor(s, off);
    float sc = p / s;

    float bv = sc; int bi = lane;
#pragma unroll
    for (int off = 32; off > 0; off >>= 1) {
        float ov = __shfl_xor(bv, off);
        int   oi = __shfl_xor(bi, off);
        if (ov > bv || (ov == bv && oi < bi)) { bv = ov; bi = oi; }
    }
    out_s[(size_t)t * NEXP + lane] = sc;
    if (lane == 0) {
        out_w[t] = bv;
        out_i[t] = (float)bi;
        atomicAdd(&out_c[bi], 1.0f);   // counts zeroed by wpack this call
    }
}

extern "C" void kernel_launch(void* const* d_in, const int* in_sizes, int n_in,
                              void* d_out, int out_size, void* d_ws, size_t ws_size,
                              hipStream_t stream)
{
    const float* x = (const float*)d_in[0];
    const float* W = (const float*)d_in[1];
    float* out = (float*)d_out;
    float* out_s = out + 2 * T_TOKENS;
    float* out_c = out + 2 * T_TOKENS + (size_t)T_TOKENS * NEXP;

    const size_t wf_bytes  = (size_t)128 * 4 * 3 * 64 * 16;           // 1.5 MiB
    const size_t per_slice = (size_t)T_TOKENS * NEXP * sizeof(float); // 2 MiB

    int S = 8;
    while (S > 1 && wf_bytes + (size_t)S * per_slice > ws_size) S >>= 1;
    float4* Wf = (float4*)d_ws;
    float* Pbuf;
    if (wf_bytes + per_slice <= ws_size) {
        Pbuf = (float*)((char*)d_ws + wf_bytes);
    } else {
        S = 1;
        Pbuf = out_s;
    }

    wpack<<<dim3(128, 4), 64, 0, stream>>>(W, Wf, out_c);
    switch (S) {
        case 8: gemm_mfma<8> <<<dim3(T_TOKENS / TB, 8), 512, 0, stream>>>(x, Wf, Pbuf); break;
        case 4: gemm_mfma<16><<<dim3(T_TOKENS / TB, 4), 512, 0, stream>>>(x, Wf, Pbuf); break;
        case 2: gemm_mfma<32><<<dim3(T_TOKENS / TB, 2), 512, 0, stream>>>(x, Wf, Pbuf); break;
        default: gemm_mfma<64><<<dim3(T_TOKENS / TB, 1), 512, 0, stream>>>(x, Wf, Pbuf); break;
    }
    switch (S) {
        case 8: router_finish_t<8><<<T_TOKENS / 4, 256, 0, stream>>>(Pbuf, out); break;
        case 4: router_finish_t<4><<<T_TOKENS / 4, 256, 0, stream>>>(Pbuf, out); break;
        case 2: router_finish_t<2><<<T_TOKENS / 4, 256, 0, stream>>>(Pbuf, out); break;
        default: router_finish_t<1><<<T_TOKENS / 4, 256, 0, stream>>>(Pbuf, out); break;
    }
}